// Round 5
// baseline (1269.845 us; speedup 1.0000x reference)
//
#include <hip/hip_runtime.h>
#include <math.h>
#include <float.h>

#define NLOC 20000
#define TT   24
#define INDIM 18
#define HH   32
#define PWN  15
#define PSTR 32   // uint stride between pooled keys (128B) to spread atomic lines

__device__ __forceinline__ unsigned int fkey(float f) {
    unsigned int b = __float_as_uint(f);
    return b ^ ((unsigned int)((int)b >> 31) | 0x80000000u);
}
__device__ __forceinline__ float funkey(unsigned int u) {
    return (u & 0x80000000u) ? __uint_as_float(u ^ 0x80000000u) : __uint_as_float(~u);
}

// ---------------- CSR build ----------------
__global__ void count_kernel(const int* __restrict__ dst, int* __restrict__ cnt, int E) {
    int e = blockIdx.x * blockDim.x + threadIdx.x;
    if (e < E) atomicAdd(&cnt[dst[e]], 1);
}

__global__ void scan_kernel(const int* __restrict__ cnt, int* __restrict__ row_ptr, int n) {
    __shared__ int sums[1024];
    const int CH = 20;
    int tid = threadIdx.x;
    int base = tid * CH;
    int local[CH];
    int s = 0;
    #pragma unroll
    for (int i = 0; i < CH; ++i) {
        int idx = base + i;
        int v = (idx < n) ? cnt[idx] : 0;
        local[i] = s;
        s += v;
    }
    sums[tid] = s;
    __syncthreads();
    for (int o = 1; o < 1024; o <<= 1) {
        int v = (tid >= o) ? sums[tid - o] : 0;
        __syncthreads();
        sums[tid] += v;
        __syncthreads();
    }
    int pre = (tid > 0) ? sums[tid - 1] : 0;
    #pragma unroll
    for (int i = 0; i < CH; ++i) {
        int idx = base + i;
        if (idx < n) row_ptr[idx] = pre + local[i];
    }
    if (tid == 1023) row_ptr[n] = sums[1023];
}

__global__ void scatter_kernel(const int* __restrict__ src, const int* __restrict__ dst,
                               const int* __restrict__ row_ptr, int* __restrict__ fill,
                               int* __restrict__ csr_src, int E) {
    int e = blockIdx.x * blockDim.x + threadIdx.x;
    if (e < E) {
        int d = dst[e];
        int pos = row_ptr[d] + atomicAdd(&fill[d], 1);
        csr_src[pos] = src[e];
    }
}

// ---------------- node transform (batched over timesteps via grid.y)
template<int IN>
__global__ void node_kernel(const float* __restrict__ xbase, long nstride, long tstride, int tadd,
                            const float* __restrict__ W, const float* __restrict__ b,
                            const float* __restrict__ aW, const float* __restrict__ ab,
                            float* __restrict__ z, float* __restrict__ es, float* __restrict__ ed) {
    __shared__ float sW[HH * IN];
    __shared__ float sb[HH];
    __shared__ float saW[2 * HH];
    __shared__ float sab;
    int tid = threadIdx.x;
    int lt = blockIdx.y;
    for (int i = tid; i < HH * IN; i += blockDim.x) sW[i] = W[i];
    if (tid < HH) sb[tid] = b[tid];
    if (tid < 2 * HH) saW[tid] = aW[tid];
    if (tid == 0) sab = ab[0];
    __syncthreads();
    int n = blockIdx.x * blockDim.x + tid;
    if (n >= NLOC) return;
    z  += (size_t)lt * NLOC * HH;
    es += (size_t)lt * NLOC;
    ed += (size_t)lt * NLOC;
    float xr[IN];
    const float* xp = xbase + (long)n * nstride + (long)(tadd + lt) * tstride;
    #pragma unroll
    for (int i = 0; i < IN; ++i) xr[i] = xp[i];
    float e_s = 0.f, e_d = sab;
    #pragma unroll
    for (int k = 0; k < HH; ++k) {
        float acc = sb[k];
        #pragma unroll
        for (int i = 0; i < IN; ++i) acc = fmaf(xr[i], sW[k * IN + i], acc);
        z[n * HH + k] = acc;
        e_s = fmaf(saW[k], acc, e_s);
        e_d = fmaf(saW[HH + k], acc, e_d);
    }
    es[n] = e_s;
    ed[n] = e_d;
}

// ---------------- per-dst attention aggregation (+elu):
// wave-per-dst; 64 (src,w) pairs from ONE coalesced csr load + es gather; denominator
// by wave shfl-reduce; pair broadcast via READLANE (compile-time lane idx -> SGPR,
// no LDS, no lgkmcnt in the loop); gathers chunked 8-deep into register arrays so
// the only waits are vmcnt with ~8 loads in flight.
template<bool WRITE_C, bool POOL>
__global__ void __launch_bounds__(256, 4)
agg_kernel(const int* __restrict__ row_ptr, const int* __restrict__ csr_src,
           const float* __restrict__ z, const float* __restrict__ es,
           const float* __restrict__ ed, float* __restrict__ cout,
           unsigned int* __restrict__ pooled_u, int tbase) {
    __shared__ float sred[4][HH];
    int lt = blockIdx.y;
    int lane = threadIdx.x & 63;
    int w    = threadIdx.x >> 6;
    int j    = lane & 31;
    int half = lane >> 5;
    int d = blockIdx.x * 4 + w;
    z  += (size_t)lt * NLOC * HH;
    es += (size_t)lt * NLOC;
    ed += (size_t)lt * NLOC;

    int beg = 0, end = 0;
    float edd = 0.f;
    if (d < NLOC) {
        beg = row_ptr[d];
        end = row_ptr[d + 1];
        edd = ed[d];
    }
    // --- preload: one coalesced idx load + one es gather, compute weight ---
    int il = beg + lane;
    bool valid = (il < end);
    int idx_l = valid ? csr_src[il] : 0;
    float ev = es[idx_l] + edd;
    ev = (ev > 0.f) ? ev : 0.01f * ev;             // leaky_relu
    float w_l = valid ? __expf(ev) : 0.f;          // unnormalized softmax weight
    int   wi_l = __float_as_int(w_l);
    // --- denominator: wave reduction (logits O(1): no max-shift needed) ---
    float den = w_l;
    #pragma unroll
    for (int o = 32; o; o >>= 1) den += __shfl_xor(den, o, 64);

    // --- gather loop: lanes 0-31 do even edges, 32-63 odd edges; 8 loads in flight ---
    const float* zj = z + j;
    float acc0 = 0.f, acc1 = 0.f, acc2 = 0.f, acc3 = 0.f;
    #pragma unroll
    for (int c = 0; c < 64; c += 16) {
        float zv[8], wv[8];
        #pragma unroll
        for (int k = 0; k < 8; ++k) {
            int e0 = c + 2 * k;
            int sa = __builtin_amdgcn_readlane(idx_l, e0);
            int sb = __builtin_amdgcn_readlane(idx_l, e0 + 1);
            int wa = __builtin_amdgcn_readlane(wi_l, e0);
            int wb = __builtin_amdgcn_readlane(wi_l, e0 + 1);
            int ss = half ? sb : sa;
            wv[k] = __int_as_float(half ? wb : wa);
            zv[k] = zj[(size_t)ss * HH];
        }
        acc0 = fmaf(wv[0], zv[0], acc0);
        acc1 = fmaf(wv[1], zv[1], acc1);
        acc2 = fmaf(wv[2], zv[2], acc2);
        acc3 = fmaf(wv[3], zv[3], acc3);
        acc0 = fmaf(wv[4], zv[4], acc0);
        acc1 = fmaf(wv[5], zv[5], acc1);
        acc2 = fmaf(wv[6], zv[6], acc2);
        acc3 = fmaf(wv[7], zv[7], acc3);
    }
    float acc = (acc0 + acc1) + (acc2 + acc3);
    // --- tail for deg > 64 (never taken on this graph; correctness only) ---
    float dent = 0.f;
    for (int i = beg + 64 + half; i < end; i += 2) {
        int s2 = csr_src[i];
        float ee = es[s2] + edd;
        ee = (ee > 0.f) ? ee : 0.01f * ee;
        float xx = __expf(ee);
        dent += xx;
        acc = fmaf(xx, zj[(size_t)s2 * HH], acc);
    }
    acc  += __shfl_xor(acc, 32, 64);
    dent += __shfl_xor(dent, 32, 64);
    den  += dent;

    float cval = -FLT_MAX;
    if (d < NLOC) {
        float v = acc / den;
        cval = (v > 0.f) ? v : expm1f(v);          // elu
        if (WRITE_C && half == 0)
            cout[(size_t)lt * NLOC * HH + (size_t)d * HH + j] = cval;
    }
    if (POOL) {
        if (half == 0) sred[w][j] = cval;
        __syncthreads();
        if (threadIdx.x < HH) {
            float m = fmaxf(fmaxf(sred[0][threadIdx.x], sred[1][threadIdx.x]),
                            fmaxf(sred[2][threadIdx.x], sred[3][threadIdx.x]));
            atomicMax(&pooled_u[(size_t)((tbase + lt) * HH + threadIdx.x) * PSTR], fkey(m));
        }
    }
}

// ---------------- GRU over all 24 steps + heads, single block
__global__ void gru_all_kernel(const unsigned int* __restrict__ pooled_u,
                               const float* __restrict__ Wih, const float* __restrict__ Whh,
                               const float* __restrict__ bih, const float* __restrict__ bhh,
                               const float* __restrict__ WI, const float* __restrict__ bI,
                               const float* __restrict__ WR, const float* __restrict__ bR,
                               const float* __restrict__ Ws, const float* __restrict__ bs,
                               const float* __restrict__ cIv, const float* __restrict__ cRv,
                               const float* __restrict__ h0, float* __restrict__ abArr,
                               float* __restrict__ out_newI, float* __restrict__ out_newR,
                               float* __restrict__ h_fin) {
    __shared__ float pooled[HH], hs[HH], gi[96], gh[96], hc[34];
    int tid = threadIdx.x;
    float wih_r[HH], whh_r[HH];
    if (tid < 96) {
        #pragma unroll
        for (int k = 0; k < HH; ++k) {
            wih_r[k] = Wih[tid * HH + k];
            whh_r[k] = Whh[tid * HH + k];
        }
    }
    if (tid < HH) hs[tid] = h0[tid];
    __syncthreads();
    for (int t = 0; t < TT; ++t) {
        if (tid < HH) pooled[tid] = funkey(pooled_u[(size_t)(t * HH + tid) * PSTR]);
        __syncthreads();
        if (tid < 96) {
            float a = bih[tid], g = bhh[tid];
            #pragma unroll
            for (int k = 0; k < HH; ++k) {
                a = fmaf(wih_r[k], pooled[k], a);
                g = fmaf(whh_r[k], hs[k], g);
            }
            gi[tid] = a; gh[tid] = g;
        }
        __syncthreads();
        if (tid < HH) {
            float r  = 1.f / (1.f + expf(-(gi[tid] + gh[tid])));
            float zg = 1.f / (1.f + expf(-(gi[HH + tid] + gh[HH + tid])));
            float nn = tanhf(gi[2 * HH + tid] + r * gh[2 * HH + tid]);
            float hn = (1.f - zg) * nn + zg * hs[tid];
            hs[tid] = hn;
            hc[tid] = hn;
        }
        if (tid == 32) hc[32] = cIv[t];
        if (tid == 33) hc[33] = cRv[t];
        __syncthreads();
        if (tid < PWN) {
            float a = bI[tid];
            #pragma unroll
            for (int k = 0; k < 34; ++k) a = fmaf(WI[tid * 34 + k], hc[k], a);
            out_newI[t * PWN + tid] = a;
        } else if (tid >= 32 && tid < 32 + PWN) {
            int p = tid - 32;
            float a = bR[p];
            #pragma unroll
            for (int k = 0; k < 34; ++k) a = fmaf(WR[p * 34 + k], hc[k], a);
            out_newR[t * PWN + p] = a;
        } else if (tid == 64 || tid == 65) {
            int p = tid - 64;
            float a = bs[p];
            #pragma unroll
            for (int k = 0; k < 34; ++k) a = fmaf(Ws[p * 34 + k], hc[k], a);
            abArr[2 * t + p] = 1.f / (1.f + expf(-a));
        }
        __syncthreads();
    }
    if (tid < HH) h_fin[tid] = hs[tid];
}

// ---------------- SIR rollout for all (n, t)
__global__ void sir_kernel(const float* __restrict__ Nin, const float* __restrict__ Iv,
                           const float* __restrict__ Rv, const float* __restrict__ abArr,
                           float* __restrict__ phyI, float* __restrict__ phyR) {
    int idx = blockIdx.x * blockDim.x + threadIdx.x; // n*TT + t
    if (idx >= NLOC * TT) return;
    int n = idx / TT, t = idx - n * TT;
    float Nv = Nin[n];
    float alpha = abArr[2 * t], beta = abArr[2 * t + 1];
    float lI = Iv[t], lR = Rv[t];
    float* oI = phyI + (size_t)idx * PWN;
    float* oR = phyR + (size_t)idx * PWN;
    #pragma unroll
    for (int p = 0; p < PWN; ++p) {
        float lS = Nv - lI - lR;
        float dI = alpha * lI * (lS / Nv) - beta * lI;
        float dR = beta * lI;
        oI[p] = dI;
        oR[p] = dR;
        lI += dI;
        lR += dR;
    }
}

extern "C" void kernel_launch(void* const* d_in, const int* in_sizes, int n_in,
                              void* d_out, int out_size, void* d_ws, size_t ws_size,
                              hipStream_t stream) {
    const float* dynamic = (const float*)d_in[0];
    const float* cIv = (const float*)d_in[1];
    const float* cRv = (const float*)d_in[2];
    const float* Nin = (const float*)d_in[3];
    const float* Iv  = (const float*)d_in[4];
    const float* Rv  = (const float*)d_in[5];
    const float* h0  = (const float*)d_in[6];
    const float* W1  = (const float*)d_in[7];
    const float* b1  = (const float*)d_in[8];
    const float* aW1 = (const float*)d_in[9];
    const float* ab1 = (const float*)d_in[10];
    const float* W2  = (const float*)d_in[11];
    const float* b2  = (const float*)d_in[12];
    const float* aW2 = (const float*)d_in[13];
    const float* ab2 = (const float*)d_in[14];
    const float* Wih = (const float*)d_in[15];
    const float* Whh = (const float*)d_in[16];
    const float* bih = (const float*)d_in[17];
    const float* bhh = (const float*)d_in[18];
    const float* WI  = (const float*)d_in[19];
    const float* bI  = (const float*)d_in[20];
    const float* WR  = (const float*)d_in[21];
    const float* bR  = (const float*)d_in[22];
    const float* Ws  = (const float*)d_in[23];
    const float* bs  = (const float*)d_in[24];
    const int* esrc  = (const int*)d_in[25];
    const int* edst  = (const int*)d_in[26];
    const int E = in_sizes[25];

    float* out = (float*)d_out;
    float* out_newI = out;                         // (1,24,15)
    float* out_newR = out + TT * PWN;              // (1,24,15)
    float* phyI = out + 2 * TT * PWN;              // (20000,24,15)
    float* phyR = phyI + (size_t)NLOC * TT * PWN;
    float* h_fin = phyR + (size_t)NLOC * TT * PWN; // (1,32)

    // ---------------- workspace layout ----------------
    char* p = (char*)d_ws;
    int* cnt = (int*)p;                 p += (size_t)NLOC * 4;
    int* fill = (int*)p;                p += (size_t)NLOC * 4;
    int* row_ptr = (int*)p;             p += (size_t)(NLOC + 2) * 4;
    int* csr = (int*)p;                 p += (size_t)E * 4;
    unsigned int* pooled_u = (unsigned int*)p; p += (size_t)TT * HH * PSTR * 4;
    float* abArr = (float*)p;           p += (size_t)2 * TT * 4;
    size_t fixed_bytes = (size_t)(p - (char*)d_ws);
    size_t per_t_bytes = (size_t)(2 * NLOC * HH + 2 * NLOC) * 4;
    int B = 1;
    if (ws_size > fixed_bytes + per_t_bytes)
        B = (int)((ws_size - fixed_bytes) / per_t_bytes);
    if (B > TT) B = TT;
    if (B < 1) B = 1;
    float* zb  = (float*)p;             // B * NLOC*HH
    float* cb  = zb + (size_t)B * NLOC * HH;
    float* esb = cb + (size_t)B * NLOC * HH;
    float* edb = esb + (size_t)B * NLOC;

    hipMemsetAsync(cnt, 0, (size_t)2 * NLOC * 4, stream);
    hipMemsetAsync(pooled_u, 0, (size_t)TT * HH * PSTR * 4, stream);

    int egrid = (E + 255) / 256;
    count_kernel<<<egrid, 256, 0, stream>>>(edst, cnt, E);
    scan_kernel<<<1, 1024, 0, stream>>>(cnt, row_ptr, NLOC);
    scatter_kernel<<<egrid, 256, 0, stream>>>(esrc, edst, row_ptr, fill, csr, E);

    const int ngrid = (NLOC + 255) / 256;   // 79
    const int agrid = (NLOC + 3) / 4;       // 5000 (256 threads = 4 waves = 4 dsts)

    for (int tbase = 0; tbase < TT; tbase += B) {
        int Bc = TT - tbase; if (Bc > B) Bc = B;
        dim3 ng(ngrid, Bc), ag(agrid, Bc);
        // layer 1
        node_kernel<INDIM><<<ng, 256, 0, stream>>>(dynamic, (long)TT * INDIM, (long)INDIM, tbase,
                                                   W1, b1, aW1, ab1, zb, esb, edb);
        agg_kernel<true, false><<<ag, 256, 0, stream>>>(row_ptr, csr, zb, esb, edb, cb, pooled_u, tbase);
        // layer 2 (no c materialization; pooled max only)
        node_kernel<HH><<<ng, 256, 0, stream>>>(cb, (long)HH, (long)NLOC * HH, 0,
                                                W2, b2, aW2, ab2, zb, esb, edb);
        agg_kernel<false, true><<<ag, 256, 0, stream>>>(row_ptr, csr, zb, esb, edb, nullptr, pooled_u, tbase);
    }

    gru_all_kernel<<<1, 128, 0, stream>>>(pooled_u, Wih, Whh, bih, bhh,
                                          WI, bI, WR, bR, Ws, bs, cIv, cRv,
                                          h0, abArr, out_newI, out_newR, h_fin);
    sir_kernel<<<(NLOC * TT + 255) / 256, 256, 0, stream>>>(Nin, Iv, Rv, abArr, phyI, phyR);
}

// Round 6
// 761.203 us; speedup vs baseline: 1.6682x; 1.6682x over previous
//
#include <hip/hip_runtime.h>
#include <hip/hip_fp16.h>
#include <math.h>
#include <float.h>

#define NLOC 20000
#define TT   24
#define INDIM 18
#define HH   32
#define PWN  15
#define PSTR 32   // uint stride between pooled keys (128B) to spread atomic lines

typedef unsigned short u16;

__device__ __forceinline__ unsigned int fkey(float f) {
    unsigned int b = __float_as_uint(f);
    return b ^ ((unsigned int)((int)b >> 31) | 0x80000000u);
}
__device__ __forceinline__ float funkey(unsigned int u) {
    return (u & 0x80000000u) ? __uint_as_float(u ^ 0x80000000u) : __uint_as_float(~u);
}

// decode XCD-swizzled flat block id: all blocks of timestep t land on XCD t%8
// (block n -> XCD n%8 round-robin heuristic). total blocks = nblk*TT, TT%8==0.
__device__ __forceinline__ void decode_t(int nblk, int swz, int tadd,
                                         int& t, int& blk, int& slice) {
    if (swz) {
        int F = blockIdx.x;
        int k = F & 7;
        int g = F >> 3;
        t = k + 8 * (g / nblk);
        blk = g % nblk;
        slice = t;
    } else {
        slice = blockIdx.y;
        t = tadd + slice;
        blk = blockIdx.x;
    }
}

// ---------------- CSR build ----------------
__global__ void count_kernel(const int* __restrict__ dst, int* __restrict__ cnt, int E) {
    int e = blockIdx.x * blockDim.x + threadIdx.x;
    if (e < E) atomicAdd(&cnt[dst[e]], 1);
}

__global__ void scan_kernel(const int* __restrict__ cnt, int* __restrict__ row_ptr, int n) {
    __shared__ int sums[1024];
    const int CH = 20;
    int tid = threadIdx.x;
    int base = tid * CH;
    int local[CH];
    int s = 0;
    #pragma unroll
    for (int i = 0; i < CH; ++i) {
        int idx = base + i;
        int v = (idx < n) ? cnt[idx] : 0;
        local[i] = s;
        s += v;
    }
    sums[tid] = s;
    __syncthreads();
    for (int o = 1; o < 1024; o <<= 1) {
        int v = (tid >= o) ? sums[tid - o] : 0;
        __syncthreads();
        sums[tid] += v;
        __syncthreads();
    }
    int pre = (tid > 0) ? sums[tid - 1] : 0;
    #pragma unroll
    for (int i = 0; i < CH; ++i) {
        int idx = base + i;
        if (idx < n) row_ptr[idx] = pre + local[i];
    }
    if (tid == 1023) row_ptr[n] = sums[1023];
}

__global__ void scatter_kernel(const int* __restrict__ src, const int* __restrict__ dst,
                               const int* __restrict__ row_ptr, int* __restrict__ fill,
                               u16* __restrict__ csr_src, int E) {
    int e = blockIdx.x * blockDim.x + threadIdx.x;
    if (e < E) {
        int d = dst[e];
        int pos = row_ptr[d] + atomicAdd(&fill[d], 1);
        csr_src[pos] = (u16)src[e];
    }
}

// ---------------- node transform; z stored fp16; XCD-swizzled
template<int IN, bool XABS, typename TIN>
__global__ void node_kernel(const TIN* __restrict__ xbase, long nstride, long tstride,
                            const float* __restrict__ W, const float* __restrict__ b,
                            const float* __restrict__ aW, const float* __restrict__ ab,
                            __half* __restrict__ z, float* __restrict__ es, float* __restrict__ ed,
                            int nblk, int swz, int tadd) {
    __shared__ float sW[HH * IN];
    __shared__ float sb[HH];
    __shared__ float saW[2 * HH];
    __shared__ float sab;
    int t, blk, slice;
    decode_t(nblk, swz, tadd, t, blk, slice);
    int tid = threadIdx.x;
    for (int i = tid; i < HH * IN; i += blockDim.x) sW[i] = W[i];
    if (tid < HH) sb[tid] = b[tid];
    if (tid < 2 * HH) saW[tid] = aW[tid];
    if (tid == 0) sab = ab[0];
    __syncthreads();
    int n = blk * blockDim.x + tid;
    if (n >= NLOC) return;
    z  += (size_t)slice * NLOC * HH;
    es += (size_t)slice * NLOC;
    ed += (size_t)slice * NLOC;
    long xoff = XABS ? (long)t * tstride : (long)slice * tstride;
    const TIN* xp = xbase + (long)n * nstride + xoff;
    float xr[IN];
    #pragma unroll
    for (int i = 0; i < IN; ++i) xr[i] = (float)xp[i];
    float e_s = 0.f, e_d = sab;
    #pragma unroll
    for (int k = 0; k < HH; ++k) {
        float acc = sb[k];
        #pragma unroll
        for (int i = 0; i < IN; ++i) acc = fmaf(xr[i], sW[k * IN + i], acc);
        z[n * HH + k] = __float2half_rn(acc);
        e_s = fmaf(saW[k], acc, e_s);
        e_d = fmaf(saW[HH + k], acc, e_d);
    }
    es[n] = e_s;
    ed[n] = e_d;
}

// ---------------- per-dst attention aggregation (+elu), fp16 z, u16 csr, XCD-swizzled
template<bool WRITE_C, bool POOL>
__global__ void __launch_bounds__(256, 4)
agg_kernel(const int* __restrict__ row_ptr, const u16* __restrict__ csr,
           const __half* __restrict__ zt, const float* __restrict__ es,
           const float* __restrict__ ed, __half* __restrict__ cout,
           unsigned int* __restrict__ pooled_u, int nblk, int swz, int tadd) {
    __shared__ int2  shp[4][64];
    __shared__ float sred[4][HH];
    int t, dblk, slice;
    decode_t(nblk, swz, tadd, t, dblk, slice);
    int lane = threadIdx.x & 63;
    int w    = threadIdx.x >> 6;
    int j    = lane & 31;
    int hv   = lane >> 5;
    int d = dblk * 4 + w;
    const __half* z   = zt + (size_t)slice * NLOC * HH;
    const float*  est = es + (size_t)slice * NLOC;
    const float*  edt = ed + (size_t)slice * NLOC;

    int beg = 0, end = 0;
    float edd = 0.f;
    if (d < NLOC) {
        beg = row_ptr[d];
        end = row_ptr[d + 1];
        edd = edt[d];
    }
    // preload: one coalesced u16 idx load + one es gather -> per-edge weight
    int il = beg + lane;
    bool valid = (il < end);
    int idx_l = valid ? (int)csr[il] : 0;
    float ev = est[idx_l] + edd;
    ev = (ev > 0.f) ? ev : 0.01f * ev;             // leaky_relu
    float w_l = valid ? __expf(ev) : 0.f;
    // denominator: wave reduction (logits O(1): shift-free softmax)
    float den = w_l;
    #pragma unroll
    for (int o = 32; o; o >>= 1) den += __shfl_xor(den, o, 64);
    shp[w][lane] = make_int2(idx_l, __float_as_int(w_l));
    __syncthreads();
    // fixed 32-edge loop per half-wave; 8 fp16 gathers batched per chunk
    float acc0 = 0.f, acc1 = 0.f, acc2 = 0.f, acc3 = 0.f;
    #pragma unroll
    for (int c = 0; c < 64; c += 16) {
        int2 pr[8];
        float zr[8];
        #pragma unroll
        for (int k2 = 0; k2 < 8; ++k2) pr[k2] = shp[w][c + 2 * k2 + hv];
        #pragma unroll
        for (int k2 = 0; k2 < 8; ++k2) zr[k2] = __half2float(z[(size_t)pr[k2].x * HH + j]);
        acc0 = fmaf(__int_as_float(pr[0].y), zr[0], acc0);
        acc1 = fmaf(__int_as_float(pr[1].y), zr[1], acc1);
        acc2 = fmaf(__int_as_float(pr[2].y), zr[2], acc2);
        acc3 = fmaf(__int_as_float(pr[3].y), zr[3], acc3);
        acc0 = fmaf(__int_as_float(pr[4].y), zr[4], acc0);
        acc1 = fmaf(__int_as_float(pr[5].y), zr[5], acc1);
        acc2 = fmaf(__int_as_float(pr[6].y), zr[6], acc2);
        acc3 = fmaf(__int_as_float(pr[7].y), zr[7], acc3);
    }
    float acc = (acc0 + acc1) + (acc2 + acc3);
    // tail for deg > 64 (not taken on this graph; correctness only)
    float dent = 0.f;
    for (int i = beg + 64 + hv; i < end; i += 2) {
        int s2 = (int)csr[i];
        float ee = est[s2] + edd;
        ee = (ee > 0.f) ? ee : 0.01f * ee;
        float xx = __expf(ee);
        dent += xx;
        acc = fmaf(xx, __half2float(z[(size_t)s2 * HH + j]), acc);
    }
    acc  += __shfl_xor(acc, 32, 64);
    dent += __shfl_xor(dent, 32, 64);
    den  += dent;

    float cval = -FLT_MAX;
    if (d < NLOC) {
        float v = acc / den;
        cval = (v > 0.f) ? v : expm1f(v);          // elu
        if (WRITE_C && hv == 0)
            cout[(size_t)slice * NLOC * HH + (size_t)d * HH + j] = __float2half_rn(cval);
    }
    if (POOL) {
        if (hv == 0) sred[w][j] = cval;
        __syncthreads();
        if (threadIdx.x < HH) {
            float m = fmaxf(fmaxf(sred[0][threadIdx.x], sred[1][threadIdx.x]),
                            fmaxf(sred[2][threadIdx.x], sred[3][threadIdx.x]));
            atomicMax(&pooled_u[(size_t)(t * HH + threadIdx.x) * PSTR], fkey(m));
        }
    }
}

// ---------------- GRU over all 24 steps + heads, single block
__global__ void gru_all_kernel(const unsigned int* __restrict__ pooled_u,
                               const float* __restrict__ Wih, const float* __restrict__ Whh,
                               const float* __restrict__ bih, const float* __restrict__ bhh,
                               const float* __restrict__ WI, const float* __restrict__ bI,
                               const float* __restrict__ WR, const float* __restrict__ bR,
                               const float* __restrict__ Ws, const float* __restrict__ bs,
                               const float* __restrict__ cIv, const float* __restrict__ cRv,
                               const float* __restrict__ h0, float* __restrict__ abArr,
                               float* __restrict__ out_newI, float* __restrict__ out_newR,
                               float* __restrict__ h_fin) {
    __shared__ float pooled[HH], hs[HH], gi[96], gh[96], hc[34];
    int tid = threadIdx.x;
    float wih_r[HH], whh_r[HH];
    if (tid < 96) {
        #pragma unroll
        for (int k = 0; k < HH; ++k) {
            wih_r[k] = Wih[tid * HH + k];
            whh_r[k] = Whh[tid * HH + k];
        }
    }
    if (tid < HH) hs[tid] = h0[tid];
    __syncthreads();
    for (int t = 0; t < TT; ++t) {
        if (tid < HH) pooled[tid] = funkey(pooled_u[(size_t)(t * HH + tid) * PSTR]);
        __syncthreads();
        if (tid < 96) {
            float a = bih[tid], g = bhh[tid];
            #pragma unroll
            for (int k = 0; k < HH; ++k) {
                a = fmaf(wih_r[k], pooled[k], a);
                g = fmaf(whh_r[k], hs[k], g);
            }
            gi[tid] = a; gh[tid] = g;
        }
        __syncthreads();
        if (tid < HH) {
            float r  = 1.f / (1.f + expf(-(gi[tid] + gh[tid])));
            float zg = 1.f / (1.f + expf(-(gi[HH + tid] + gh[HH + tid])));
            float nn = tanhf(gi[2 * HH + tid] + r * gh[2 * HH + tid]);
            float hn = (1.f - zg) * nn + zg * hs[tid];
            hs[tid] = hn;
            hc[tid] = hn;
        }
        if (tid == 32) hc[32] = cIv[t];
        if (tid == 33) hc[33] = cRv[t];
        __syncthreads();
        if (tid < PWN) {
            float a = bI[tid];
            #pragma unroll
            for (int k = 0; k < 34; ++k) a = fmaf(WI[tid * 34 + k], hc[k], a);
            out_newI[t * PWN + tid] = a;
        } else if (tid >= 32 && tid < 32 + PWN) {
            int p = tid - 32;
            float a = bR[p];
            #pragma unroll
            for (int k = 0; k < 34; ++k) a = fmaf(WR[p * 34 + k], hc[k], a);
            out_newR[t * PWN + p] = a;
        } else if (tid == 64 || tid == 65) {
            int p = tid - 64;
            float a = bs[p];
            #pragma unroll
            for (int k = 0; k < 34; ++k) a = fmaf(Ws[p * 34 + k], hc[k], a);
            abArr[2 * t + p] = 1.f / (1.f + expf(-a));
        }
        __syncthreads();
    }
    if (tid < HH) h_fin[tid] = hs[tid];
}

// ---------------- SIR rollout for all (n, t)
__global__ void sir_kernel(const float* __restrict__ Nin, const float* __restrict__ Iv,
                           const float* __restrict__ Rv, const float* __restrict__ abArr,
                           float* __restrict__ phyI, float* __restrict__ phyR) {
    int idx = blockIdx.x * blockDim.x + threadIdx.x; // n*TT + t
    if (idx >= NLOC * TT) return;
    int n = idx / TT, t = idx - n * TT;
    float Nv = Nin[n];
    float alpha = abArr[2 * t], beta = abArr[2 * t + 1];
    float lI = Iv[t], lR = Rv[t];
    float* oI = phyI + (size_t)idx * PWN;
    float* oR = phyR + (size_t)idx * PWN;
    #pragma unroll
    for (int p = 0; p < PWN; ++p) {
        float lS = Nv - lI - lR;
        float dI = alpha * lI * (lS / Nv) - beta * lI;
        float dR = beta * lI;
        oI[p] = dI;
        oR[p] = dR;
        lI += dI;
        lR += dR;
    }
}

extern "C" void kernel_launch(void* const* d_in, const int* in_sizes, int n_in,
                              void* d_out, int out_size, void* d_ws, size_t ws_size,
                              hipStream_t stream) {
    const float* dynamic = (const float*)d_in[0];
    const float* cIv = (const float*)d_in[1];
    const float* cRv = (const float*)d_in[2];
    const float* Nin = (const float*)d_in[3];
    const float* Iv  = (const float*)d_in[4];
    const float* Rv  = (const float*)d_in[5];
    const float* h0  = (const float*)d_in[6];
    const float* W1  = (const float*)d_in[7];
    const float* b1  = (const float*)d_in[8];
    const float* aW1 = (const float*)d_in[9];
    const float* ab1 = (const float*)d_in[10];
    const float* W2  = (const float*)d_in[11];
    const float* b2  = (const float*)d_in[12];
    const float* aW2 = (const float*)d_in[13];
    const float* ab2 = (const float*)d_in[14];
    const float* Wih = (const float*)d_in[15];
    const float* Whh = (const float*)d_in[16];
    const float* bih = (const float*)d_in[17];
    const float* bhh = (const float*)d_in[18];
    const float* WI  = (const float*)d_in[19];
    const float* bI  = (const float*)d_in[20];
    const float* WR  = (const float*)d_in[21];
    const float* bR  = (const float*)d_in[22];
    const float* Ws  = (const float*)d_in[23];
    const float* bs  = (const float*)d_in[24];
    const int* esrc  = (const int*)d_in[25];
    const int* edst  = (const int*)d_in[26];
    const int E = in_sizes[25];

    float* out = (float*)d_out;
    float* out_newI = out;                         // (1,24,15)
    float* out_newR = out + TT * PWN;              // (1,24,15)
    float* phyI = out + 2 * TT * PWN;              // (20000,24,15)
    float* phyR = phyI + (size_t)NLOC * TT * PWN;
    float* h_fin = phyR + (size_t)NLOC * TT * PWN; // (1,32)

    // ---------------- workspace layout ----------------
    char* p = (char*)d_ws;
    int* cnt = (int*)p;                 p += (size_t)NLOC * 4;
    int* fill = (int*)p;                p += (size_t)NLOC * 4;
    int* row_ptr = (int*)p;             p += (size_t)(NLOC + 2) * 4;
    u16* csr = (u16*)p;                 p += ((size_t)E * 2 + 3) & ~(size_t)3;
    unsigned int* pooled_u = (unsigned int*)p; p += (size_t)TT * HH * PSTR * 4;
    float* abArr = (float*)p;           p += (size_t)2 * TT * 4;
    size_t fixed_bytes = (size_t)(p - (char*)d_ws);
    size_t per_t_bytes = (size_t)(2 * NLOC * HH * 2 + 2 * NLOC * 4);
    int B = 1;
    if (ws_size > fixed_bytes + per_t_bytes)
        B = (int)((ws_size - fixed_bytes) / per_t_bytes);
    if (B > TT) B = TT;
    if (B < 1) B = 1;
    __half* zb  = (__half*)p;                       // B * NLOC*HH fp16
    __half* cb  = zb + (size_t)B * NLOC * HH;       // B * NLOC*HH fp16
    float* esb  = (float*)(cb + (size_t)B * NLOC * HH);
    float* edb  = esb + (size_t)B * NLOC;

    hipMemsetAsync(cnt, 0, (size_t)2 * NLOC * 4, stream);
    hipMemsetAsync(pooled_u, 0, (size_t)TT * HH * PSTR * 4, stream);

    int egrid = (E + 255) / 256;
    count_kernel<<<egrid, 256, 0, stream>>>(edst, cnt, E);
    scan_kernel<<<1, 1024, 0, stream>>>(cnt, row_ptr, NLOC);
    scatter_kernel<<<egrid, 256, 0, stream>>>(esrc, edst, row_ptr, fill, csr, E);

    const int NBLK_N = (NLOC + 255) / 256;   // 79
    const int NBLK_A = (NLOC + 3) / 4;       // 5000

    if (B >= TT) {
        // full batch: XCD-swizzled flat grids (all work for t on XCD t%8)
        dim3 ng(NBLK_N * TT), ag(NBLK_A * TT);
        node_kernel<INDIM, true, float><<<ng, 256, 0, stream>>>(
            dynamic, (long)TT * INDIM, (long)INDIM, W1, b1, aW1, ab1,
            zb, esb, edb, NBLK_N, 1, 0);
        agg_kernel<true, false><<<ag, 256, 0, stream>>>(
            row_ptr, csr, zb, esb, edb, cb, pooled_u, NBLK_A, 1, 0);
        node_kernel<HH, false, __half><<<ng, 256, 0, stream>>>(
            cb, (long)HH, (long)NLOC * HH, W2, b2, aW2, ab2,
            zb, esb, edb, NBLK_N, 1, 0);
        agg_kernel<false, true><<<ag, 256, 0, stream>>>(
            row_ptr, csr, zb, esb, edb, nullptr, pooled_u, NBLK_A, 1, 0);
    } else {
        for (int tbase = 0; tbase < TT; tbase += B) {
            int Bc = TT - tbase; if (Bc > B) Bc = B;
            dim3 ng(NBLK_N, Bc), ag(NBLK_A, Bc);
            node_kernel<INDIM, true, float><<<ng, 256, 0, stream>>>(
                dynamic, (long)TT * INDIM, (long)INDIM, W1, b1, aW1, ab1,
                zb, esb, edb, NBLK_N, 0, tbase);
            agg_kernel<true, false><<<ag, 256, 0, stream>>>(
                row_ptr, csr, zb, esb, edb, cb, pooled_u, NBLK_A, 0, tbase);
            node_kernel<HH, false, __half><<<ng, 256, 0, stream>>>(
                cb, (long)HH, (long)NLOC * HH, W2, b2, aW2, ab2,
                zb, esb, edb, NBLK_N, 0, tbase);
            agg_kernel<false, true><<<ag, 256, 0, stream>>>(
                row_ptr, csr, zb, esb, edb, nullptr, pooled_u, NBLK_A, 0, tbase);
        }
    }

    gru_all_kernel<<<1, 128, 0, stream>>>(pooled_u, Wih, Whh, bih, bhh,
                                          WI, bI, WR, bR, Ws, bs, cIv, cRv,
                                          h0, abArr, out_newI, out_newR, h_fin);
    sir_kernel<<<(NLOC * TT + 255) / 256, 256, 0, stream>>>(Nin, Iv, Rv, abArr, phyI, phyR);
}

// Round 7
// 749.404 us; speedup vs baseline: 1.6945x; 1.0157x over previous
//
#include <hip/hip_runtime.h>
#include <hip/hip_fp16.h>
#include <math.h>
#include <float.h>
#include <type_traits>

#define NLOC 20000
#define TT   24
#define INDIM 18
#define HH   32
#define PWN  15
#define PSTR 32   // uint stride between pooled keys (128B) to spread atomic lines

typedef unsigned short u16;

__device__ __forceinline__ unsigned int fkey(float f) {
    unsigned int b = __float_as_uint(f);
    return b ^ ((unsigned int)((int)b >> 31) | 0x80000000u);
}
__device__ __forceinline__ float funkey(unsigned int u) {
    return (u & 0x80000000u) ? __uint_as_float(u ^ 0x80000000u) : __uint_as_float(~u);
}

// decode XCD-swizzled flat block id: all blocks of timestep t land on XCD t%8
__device__ __forceinline__ void decode_t(int nblk, int swz, int tadd,
                                         int& t, int& blk, int& slice) {
    if (swz) {
        int F = blockIdx.x;
        int k = F & 7;
        int g = F >> 3;
        t = k + 8 * (g / nblk);
        blk = g % nblk;
        slice = t;
    } else {
        slice = blockIdx.y;
        t = tadd + slice;
        blk = blockIdx.x;
    }
}

// ---------------- CSR build ----------------
__global__ void count_kernel(const int* __restrict__ dst, int* __restrict__ cnt, int E) {
    int e = blockIdx.x * blockDim.x + threadIdx.x;
    if (e < E) atomicAdd(&cnt[dst[e]], 1);
}

__global__ void scan_kernel(const int* __restrict__ cnt, int* __restrict__ row_ptr, int n) {
    __shared__ int sums[1024];
    const int CH = 20;
    int tid = threadIdx.x;
    int base = tid * CH;
    int local[CH];
    int s = 0;
    #pragma unroll
    for (int i = 0; i < CH; ++i) {
        int idx = base + i;
        int v = (idx < n) ? cnt[idx] : 0;
        local[i] = s;
        s += v;
    }
    sums[tid] = s;
    __syncthreads();
    for (int o = 1; o < 1024; o <<= 1) {
        int v = (tid >= o) ? sums[tid - o] : 0;
        __syncthreads();
        sums[tid] += v;
        __syncthreads();
    }
    int pre = (tid > 0) ? sums[tid - 1] : 0;
    #pragma unroll
    for (int i = 0; i < CH; ++i) {
        int idx = base + i;
        if (idx < n) row_ptr[idx] = pre + local[i];
    }
    if (tid == 1023) row_ptr[n] = sums[1023];
}

__global__ void scatter_kernel(const int* __restrict__ src, const int* __restrict__ dst,
                               const int* __restrict__ row_ptr, int* __restrict__ fill,
                               u16* __restrict__ csr_src, int E) {
    int e = blockIdx.x * blockDim.x + threadIdx.x;
    if (e < E) {
        int d = dst[e];
        int pos = row_ptr[d] + atomicAdd(&fill[d], 1);
        csr_src[pos] = (u16)src[e];
    }
}

// ---------------- node transform; z stored fp16; XCD-swizzled
template<int IN, bool XABS, typename TIN>
__global__ void node_kernel(const TIN* __restrict__ xbase, long nstride, long tstride,
                            const float* __restrict__ W, const float* __restrict__ b,
                            const float* __restrict__ aW, const float* __restrict__ ab,
                            __half* __restrict__ z, float* __restrict__ es, float* __restrict__ ed,
                            int nblk, int swz, int tadd) {
    __shared__ float sW[HH * IN];
    __shared__ float sb[HH];
    __shared__ float saW[2 * HH];
    __shared__ float sab;
    int t, blk, slice;
    decode_t(nblk, swz, tadd, t, blk, slice);
    int tid = threadIdx.x;
    for (int i = tid; i < HH * IN; i += blockDim.x) sW[i] = W[i];
    if (tid < HH) sb[tid] = b[tid];
    if (tid < 2 * HH) saW[tid] = aW[tid];
    if (tid == 0) sab = ab[0];
    __syncthreads();
    int n = blk * blockDim.x + tid;
    if (n >= NLOC) return;
    z  += (size_t)slice * NLOC * HH;
    es += (size_t)slice * NLOC;
    ed += (size_t)slice * NLOC;
    long xoff = XABS ? (long)t * tstride : (long)slice * tstride;
    const TIN* xp = xbase + (long)n * nstride + xoff;
    float xr[IN];
    if constexpr (std::is_same<TIN, __half>::value) {
        const __half2* hp = (const __half2*)xp;
        #pragma unroll
        for (int i = 0; i < IN / 2; ++i) {
            float2 f = __half22float2(hp[i]);
            xr[2 * i] = f.x; xr[2 * i + 1] = f.y;
        }
    } else {
        #pragma unroll
        for (int i = 0; i < IN; ++i) xr[i] = (float)xp[i];
    }
    float e_s = 0.f, e_d = sab;
    #pragma unroll
    for (int k = 0; k < HH; ++k) {
        float acc = sb[k];
        #pragma unroll
        for (int i = 0; i < IN; ++i) acc = fmaf(xr[i], sW[k * IN + i], acc);
        z[n * HH + k] = __float2half_rn(acc);
        e_s = fmaf(saW[k], acc, e_s);
        e_d = fmaf(saW[HH + k], acc, e_d);
    }
    es[n] = e_s;
    ed[n] = e_d;
}

// ---------------- per-dst attention aggregation (+elu), fp16 z, u16 csr, XCD-swizzled.
// Wave = 8 edge-rows x 8 dim-groups: each lane loads 4 dims (dwordx2) of one edge
// per pass -> 8 passes cover 64 edges; 3-step shfl_xor folds edge-rows.
template<bool WRITE_C, bool POOL>
__global__ void __launch_bounds__(256, 4)
agg_kernel(const int* __restrict__ row_ptr, const u16* __restrict__ csr,
           const __half* __restrict__ zt, const float* __restrict__ es,
           const float* __restrict__ ed, __half* __restrict__ cout,
           unsigned int* __restrict__ pooled_u, int nblk, int swz, int tadd) {
    __shared__ int2  shp[4][64];
    __shared__ float sred[4][HH];
    int t, dblk, slice;
    decode_t(nblk, swz, tadd, t, dblk, slice);
    int lane = threadIdx.x & 63;
    int w    = threadIdx.x >> 6;
    int r    = lane >> 3;     // edge-row 0..7
    int cg   = lane & 7;      // dim-group: dims cg*4 .. cg*4+3
    int d = dblk * 4 + w;
    const __half* z   = zt + (size_t)slice * NLOC * HH;
    const float*  est = es + (size_t)slice * NLOC;
    const float*  edt = ed + (size_t)slice * NLOC;

    int beg = 0, end = 0;
    float edd = 0.f;
    if (d < NLOC) {
        beg = row_ptr[d];
        end = row_ptr[d + 1];
        edd = edt[d];
    }
    int deg = end - beg;
    // preload: one coalesced u16 idx load + one es gather -> per-edge weight
    int il = beg + lane;
    bool valid = (il < end);
    int idx_l = valid ? (int)csr[il] : 0;
    float ev = est[idx_l] + edd;
    ev = (ev > 0.f) ? ev : 0.01f * ev;             // leaky_relu
    float w_l = valid ? __expf(ev) : 0.f;
    // denominator over first 64 edges: full-wave reduction (shift-free softmax)
    float den = w_l;
    #pragma unroll
    for (int o = 32; o; o >>= 1) den += __shfl_xor(den, o, 64);
    shp[w][lane] = make_int2(idx_l, __float_as_int(w_l));
    __syncthreads();

    // main loop: 8 passes x (1 LDS pair read + 1 dwordx2 z load + 4 fma)
    float a0 = 0.f, a1 = 0.f, a2 = 0.f, a3 = 0.f;
    #pragma unroll
    for (int pass = 0; pass < 8; ++pass) {
        int2 pw = shp[w][pass * 8 + r];
        float we = __int_as_float(pw.y);
        const __half2* zp = (const __half2*)(z + (size_t)pw.x * HH + cg * 4);
        __half2 h01 = zp[0], h23 = zp[1];
        a0 = fmaf(we, __half2float(__low2half(h01)),  a0);
        a1 = fmaf(we, __half2float(__high2half(h01)), a1);
        a2 = fmaf(we, __half2float(__low2half(h23)),  a2);
        a3 = fmaf(we, __half2float(__high2half(h23)), a3);
    }
    // tail for deg > 64 (not taken on this graph; correctness only)
    float dent = 0.f;
    for (int e = 64 + r; e < deg; e += 8) {
        int s2 = (int)csr[beg + e];
        float ee = est[s2] + edd;
        ee = (ee > 0.f) ? ee : 0.01f * ee;
        float xx = __expf(ee);
        dent += xx;
        const __half2* zp = (const __half2*)(z + (size_t)s2 * HH + cg * 4);
        __half2 h01 = zp[0], h23 = zp[1];
        a0 = fmaf(xx, __half2float(__low2half(h01)),  a0);
        a1 = fmaf(xx, __half2float(__high2half(h01)), a1);
        a2 = fmaf(xx, __half2float(__low2half(h23)),  a2);
        a3 = fmaf(xx, __half2float(__high2half(h23)), a3);
    }
    // fold edge-rows (strides 8,16,32); dent identical across cg, reduced the same way
    #pragma unroll
    for (int o = 8; o <= 32; o <<= 1) {
        a0 += __shfl_xor(a0, o, 64);
        a1 += __shfl_xor(a1, o, 64);
        a2 += __shfl_xor(a2, o, 64);
        a3 += __shfl_xor(a3, o, 64);
        dent += __shfl_xor(dent, o, 64);
    }
    den += dent;

    float v0 = -FLT_MAX, v1 = -FLT_MAX, v2 = -FLT_MAX, v3 = -FLT_MAX;
    if (d < NLOC) {
        float rden = 1.f / den;
        v0 = a0 * rden; v0 = (v0 > 0.f) ? v0 : expm1f(v0);
        v1 = a1 * rden; v1 = (v1 > 0.f) ? v1 : expm1f(v1);
        v2 = a2 * rden; v2 = (v2 > 0.f) ? v2 : expm1f(v2);
        v3 = a3 * rden; v3 = (v3 > 0.f) ? v3 : expm1f(v3);
        if (WRITE_C && r == 0) {
            __half2 o01 = __floats2half2_rn(v0, v1);
            __half2 o23 = __floats2half2_rn(v2, v3);
            uint2 pk;
            pk.x = *(unsigned int*)&o01;
            pk.y = *(unsigned int*)&o23;
            *(uint2*)&cout[(size_t)slice * NLOC * HH + (size_t)d * HH + cg * 4] = pk;
        }
    }
    if (POOL) {
        if (r == 0) {
            sred[w][cg * 4 + 0] = v0;
            sred[w][cg * 4 + 1] = v1;
            sred[w][cg * 4 + 2] = v2;
            sred[w][cg * 4 + 3] = v3;
        }
        __syncthreads();
        if (threadIdx.x < HH) {
            float m = fmaxf(fmaxf(sred[0][threadIdx.x], sred[1][threadIdx.x]),
                            fmaxf(sred[2][threadIdx.x], sred[3][threadIdx.x]));
            atomicMax(&pooled_u[(size_t)(t * HH + threadIdx.x) * PSTR], fkey(m));
        }
    }
}

// ---------------- GRU over all 24 steps + heads, single block
__global__ void gru_all_kernel(const unsigned int* __restrict__ pooled_u,
                               const float* __restrict__ Wih, const float* __restrict__ Whh,
                               const float* __restrict__ bih, const float* __restrict__ bhh,
                               const float* __restrict__ WI, const float* __restrict__ bI,
                               const float* __restrict__ WR, const float* __restrict__ bR,
                               const float* __restrict__ Ws, const float* __restrict__ bs,
                               const float* __restrict__ cIv, const float* __restrict__ cRv,
                               const float* __restrict__ h0, float* __restrict__ abArr,
                               float* __restrict__ out_newI, float* __restrict__ out_newR,
                               float* __restrict__ h_fin) {
    __shared__ float pooled[HH], hs[HH], gi[96], gh[96], hc[34];
    int tid = threadIdx.x;
    float wih_r[HH], whh_r[HH];
    if (tid < 96) {
        #pragma unroll
        for (int k = 0; k < HH; ++k) {
            wih_r[k] = Wih[tid * HH + k];
            whh_r[k] = Whh[tid * HH + k];
        }
    }
    if (tid < HH) hs[tid] = h0[tid];
    __syncthreads();
    for (int t = 0; t < TT; ++t) {
        if (tid < HH) pooled[tid] = funkey(pooled_u[(size_t)(t * HH + tid) * PSTR]);
        __syncthreads();
        if (tid < 96) {
            float a = bih[tid], g = bhh[tid];
            #pragma unroll
            for (int k = 0; k < HH; ++k) {
                a = fmaf(wih_r[k], pooled[k], a);
                g = fmaf(whh_r[k], hs[k], g);
            }
            gi[tid] = a; gh[tid] = g;
        }
        __syncthreads();
        if (tid < HH) {
            float r  = 1.f / (1.f + expf(-(gi[tid] + gh[tid])));
            float zg = 1.f / (1.f + expf(-(gi[HH + tid] + gh[HH + tid])));
            float nn = tanhf(gi[2 * HH + tid] + r * gh[2 * HH + tid]);
            float hn = (1.f - zg) * nn + zg * hs[tid];
            hs[tid] = hn;
            hc[tid] = hn;
        }
        if (tid == 32) hc[32] = cIv[t];
        if (tid == 33) hc[33] = cRv[t];
        __syncthreads();
        if (tid < PWN) {
            float a = bI[tid];
            #pragma unroll
            for (int k = 0; k < 34; ++k) a = fmaf(WI[tid * 34 + k], hc[k], a);
            out_newI[t * PWN + tid] = a;
        } else if (tid >= 32 && tid < 32 + PWN) {
            int p = tid - 32;
            float a = bR[p];
            #pragma unroll
            for (int k = 0; k < 34; ++k) a = fmaf(WR[p * 34 + k], hc[k], a);
            out_newR[t * PWN + p] = a;
        } else if (tid == 64 || tid == 65) {
            int p = tid - 64;
            float a = bs[p];
            #pragma unroll
            for (int k = 0; k < 34; ++k) a = fmaf(Ws[p * 34 + k], hc[k], a);
            abArr[2 * t + p] = 1.f / (1.f + expf(-a));
        }
        __syncthreads();
    }
    if (tid < HH) h_fin[tid] = hs[tid];
}

// ---------------- SIR rollout for all (n, t)
__global__ void sir_kernel(const float* __restrict__ Nin, const float* __restrict__ Iv,
                           const float* __restrict__ Rv, const float* __restrict__ abArr,
                           float* __restrict__ phyI, float* __restrict__ phyR) {
    int idx = blockIdx.x * blockDim.x + threadIdx.x; // n*TT + t
    if (idx >= NLOC * TT) return;
    int n = idx / TT, t = idx - n * TT;
    float Nv = Nin[n];
    float alpha = abArr[2 * t], beta = abArr[2 * t + 1];
    float lI = Iv[t], lR = Rv[t];
    float* oI = phyI + (size_t)idx * PWN;
    float* oR = phyR + (size_t)idx * PWN;
    #pragma unroll
    for (int p = 0; p < PWN; ++p) {
        float lS = Nv - lI - lR;
        float dI = alpha * lI * (lS / Nv) - beta * lI;
        float dR = beta * lI;
        oI[p] = dI;
        oR[p] = dR;
        lI += dI;
        lR += dR;
    }
}

extern "C" void kernel_launch(void* const* d_in, const int* in_sizes, int n_in,
                              void* d_out, int out_size, void* d_ws, size_t ws_size,
                              hipStream_t stream) {
    const float* dynamic = (const float*)d_in[0];
    const float* cIv = (const float*)d_in[1];
    const float* cRv = (const float*)d_in[2];
    const float* Nin = (const float*)d_in[3];
    const float* Iv  = (const float*)d_in[4];
    const float* Rv  = (const float*)d_in[5];
    const float* h0  = (const float*)d_in[6];
    const float* W1  = (const float*)d_in[7];
    const float* b1  = (const float*)d_in[8];
    const float* aW1 = (const float*)d_in[9];
    const float* ab1 = (const float*)d_in[10];
    const float* W2  = (const float*)d_in[11];
    const float* b2  = (const float*)d_in[12];
    const float* aW2 = (const float*)d_in[13];
    const float* ab2 = (const float*)d_in[14];
    const float* Wih = (const float*)d_in[15];
    const float* Whh = (const float*)d_in[16];
    const float* bih = (const float*)d_in[17];
    const float* bhh = (const float*)d_in[18];
    const float* WI  = (const float*)d_in[19];
    const float* bI  = (const float*)d_in[20];
    const float* WR  = (const float*)d_in[21];
    const float* bR  = (const float*)d_in[22];
    const float* Ws  = (const float*)d_in[23];
    const float* bs  = (const float*)d_in[24];
    const int* esrc  = (const int*)d_in[25];
    const int* edst  = (const int*)d_in[26];
    const int E = in_sizes[25];

    float* out = (float*)d_out;
    float* out_newI = out;                         // (1,24,15)
    float* out_newR = out + TT * PWN;              // (1,24,15)
    float* phyI = out + 2 * TT * PWN;              // (20000,24,15)
    float* phyR = phyI + (size_t)NLOC * TT * PWN;
    float* h_fin = phyR + (size_t)NLOC * TT * PWN; // (1,32)

    // ---------------- workspace layout ----------------
    char* p = (char*)d_ws;
    int* cnt = (int*)p;                 p += (size_t)NLOC * 4;
    int* fill = (int*)p;                p += (size_t)NLOC * 4;
    int* row_ptr = (int*)p;             p += (size_t)(NLOC + 2) * 4;
    u16* csr = (u16*)p;                 p += ((size_t)E * 2 + 15) & ~(size_t)15;
    unsigned int* pooled_u = (unsigned int*)p; p += (size_t)TT * HH * PSTR * 4;
    float* abArr = (float*)p;           p += (size_t)2 * TT * 4;
    p = (char*)(((size_t)p + 15) & ~(size_t)15);
    size_t fixed_bytes = (size_t)(p - (char*)d_ws);
    size_t per_t_bytes = (size_t)(2 * NLOC * HH * 2 + 2 * NLOC * 4);
    int B = 1;
    if (ws_size > fixed_bytes + per_t_bytes)
        B = (int)((ws_size - fixed_bytes) / per_t_bytes);
    if (B > TT) B = TT;
    if (B < 1) B = 1;
    __half* zb  = (__half*)p;                       // B * NLOC*HH fp16
    __half* cb  = zb + (size_t)B * NLOC * HH;       // B * NLOC*HH fp16
    float* esb  = (float*)(cb + (size_t)B * NLOC * HH);
    float* edb  = esb + (size_t)B * NLOC;

    hipMemsetAsync(cnt, 0, (size_t)2 * NLOC * 4, stream);
    hipMemsetAsync(pooled_u, 0, (size_t)TT * HH * PSTR * 4, stream);

    int egrid = (E + 255) / 256;
    count_kernel<<<egrid, 256, 0, stream>>>(edst, cnt, E);
    scan_kernel<<<1, 1024, 0, stream>>>(cnt, row_ptr, NLOC);
    scatter_kernel<<<egrid, 256, 0, stream>>>(esrc, edst, row_ptr, fill, csr, E);

    const int NBLK_N = (NLOC + 255) / 256;   // 79
    const int NBLK_A = (NLOC + 3) / 4;       // 5000

    if (B >= TT) {
        // full batch: XCD-swizzled flat grids (all work for t on XCD t%8)
        dim3 ng(NBLK_N * TT), ag(NBLK_A * TT);
        node_kernel<INDIM, true, float><<<ng, 256, 0, stream>>>(
            dynamic, (long)TT * INDIM, (long)INDIM, W1, b1, aW1, ab1,
            zb, esb, edb, NBLK_N, 1, 0);
        agg_kernel<true, false><<<ag, 256, 0, stream>>>(
            row_ptr, csr, zb, esb, edb, cb, pooled_u, NBLK_A, 1, 0);
        node_kernel<HH, false, __half><<<ng, 256, 0, stream>>>(
            cb, (long)HH, (long)NLOC * HH, W2, b2, aW2, ab2,
            zb, esb, edb, NBLK_N, 1, 0);
        agg_kernel<false, true><<<ag, 256, 0, stream>>>(
            row_ptr, csr, zb, esb, edb, nullptr, pooled_u, NBLK_A, 1, 0);
    } else {
        for (int tbase = 0; tbase < TT; tbase += B) {
            int Bc = TT - tbase; if (Bc > B) Bc = B;
            dim3 ng(NBLK_N, Bc), ag(NBLK_A, Bc);
            node_kernel<INDIM, true, float><<<ng, 256, 0, stream>>>(
                dynamic, (long)TT * INDIM, (long)INDIM, W1, b1, aW1, ab1,
                zb, esb, edb, NBLK_N, 0, tbase);
            agg_kernel<true, false><<<ag, 256, 0, stream>>>(
                row_ptr, csr, zb, esb, edb, cb, pooled_u, NBLK_A, 0, tbase);
            node_kernel<HH, false, __half><<<ng, 256, 0, stream>>>(
                cb, (long)HH, (long)NLOC * HH, W2, b2, aW2, ab2,
                zb, esb, edb, NBLK_N, 0, tbase);
            agg_kernel<false, true><<<ag, 256, 0, stream>>>(
                row_ptr, csr, zb, esb, edb, nullptr, pooled_u, NBLK_A, 0, tbase);
        }
    }

    gru_all_kernel<<<1, 128, 0, stream>>>(pooled_u, Wih, Whh, bih, bhh,
                                          WI, bI, WR, bR, Ws, bs, cIv, cRv,
                                          h0, abArr, out_newI, out_newR, h_fin);
    sir_kernel<<<(NLOC * TT + 255) / 256, 256, 0, stream>>>(Nin, Iv, Rv, abArr, phyI, phyR);
}

// Round 8
// 706.729 us; speedup vs baseline: 1.7968x; 1.0604x over previous
//
#include <hip/hip_runtime.h>
#include <hip/hip_fp16.h>
#include <math.h>
#include <float.h>
#include <type_traits>

#define NLOC 20000
#define TT   24
#define INDIM 18
#define HH   32
#define PWN  15
#define PSTR 32   // uint stride between pooled keys (128B) to spread atomic lines

typedef unsigned short u16;

__device__ __forceinline__ unsigned int fkey(float f) {
    unsigned int b = __float_as_uint(f);
    return b ^ ((unsigned int)((int)b >> 31) | 0x80000000u);
}
__device__ __forceinline__ float funkey(unsigned int u) {
    return (u & 0x80000000u) ? __uint_as_float(u ^ 0x80000000u) : __uint_as_float(~u);
}

// decode XCD-swizzled flat block id: all blocks of timestep t land on XCD t%8
__device__ __forceinline__ void decode_t(int nblk, int swz, int tadd,
                                         int& t, int& blk, int& slice) {
    if (swz) {
        int F = blockIdx.x;
        int k = F & 7;
        int g = F >> 3;
        t = k + 8 * (g / nblk);
        blk = g % nblk;
        slice = t;
    } else {
        slice = blockIdx.y;
        t = tadd + slice;
        blk = blockIdx.x;
    }
}

// ---------------- CSR build ----------------
__global__ void count_kernel(const int* __restrict__ dst, int* __restrict__ cnt, int E) {
    int e = blockIdx.x * blockDim.x + threadIdx.x;
    if (e < E) atomicAdd(&cnt[dst[e]], 1);
}

__global__ void scan_kernel(const int* __restrict__ cnt, int* __restrict__ row_ptr, int n) {
    __shared__ int sums[1024];
    const int CH = 20;
    int tid = threadIdx.x;
    int base = tid * CH;
    int local[CH];
    int s = 0;
    #pragma unroll
    for (int i = 0; i < CH; ++i) {
        int idx = base + i;
        int v = (idx < n) ? cnt[idx] : 0;
        local[i] = s;
        s += v;
    }
    sums[tid] = s;
    __syncthreads();
    for (int o = 1; o < 1024; o <<= 1) {
        int v = (tid >= o) ? sums[tid - o] : 0;
        __syncthreads();
        sums[tid] += v;
        __syncthreads();
    }
    int pre = (tid > 0) ? sums[tid - 1] : 0;
    #pragma unroll
    for (int i = 0; i < CH; ++i) {
        int idx = base + i;
        if (idx < n) row_ptr[idx] = pre + local[i];
    }
    if (tid == 1023) row_ptr[n] = sums[1023];
}

__global__ void scatter_kernel(const int* __restrict__ src, const int* __restrict__ dst,
                               const int* __restrict__ row_ptr, int* __restrict__ fill,
                               u16* __restrict__ csr_src, int E) {
    int e = blockIdx.x * blockDim.x + threadIdx.x;
    if (e < E) {
        int d = dst[e];
        int pos = row_ptr[d] + atomicAdd(&fill[d], 1);
        csr_src[pos] = (u16)src[e];
    }
}

// ---------------- node transform; z stored fp16; XCD-swizzled
template<int IN, bool XABS, typename TIN>
__global__ void node_kernel(const TIN* __restrict__ xbase, long nstride, long tstride,
                            const float* __restrict__ W, const float* __restrict__ b,
                            const float* __restrict__ aW, const float* __restrict__ ab,
                            __half* __restrict__ z, float* __restrict__ es, float* __restrict__ ed,
                            int nblk, int swz, int tadd) {
    __shared__ float sW[HH * IN];
    __shared__ float sb[HH];
    __shared__ float saW[2 * HH];
    __shared__ float sab;
    int t, blk, slice;
    decode_t(nblk, swz, tadd, t, blk, slice);
    int tid = threadIdx.x;
    for (int i = tid; i < HH * IN; i += blockDim.x) sW[i] = W[i];
    if (tid < HH) sb[tid] = b[tid];
    if (tid < 2 * HH) saW[tid] = aW[tid];
    if (tid == 0) sab = ab[0];
    __syncthreads();
    int n = blk * blockDim.x + tid;
    if (n >= NLOC) return;
    z  += (size_t)slice * NLOC * HH;
    es += (size_t)slice * NLOC;
    ed += (size_t)slice * NLOC;
    long xoff = XABS ? (long)t * tstride : (long)slice * tstride;
    const TIN* xp = xbase + (long)n * nstride + xoff;
    float xr[IN];
    if constexpr (std::is_same<TIN, __half>::value) {
        const __half2* hp = (const __half2*)xp;
        #pragma unroll
        for (int i = 0; i < IN / 2; ++i) {
            float2 f = __half22float2(hp[i]);
            xr[2 * i] = f.x; xr[2 * i + 1] = f.y;
        }
    } else {
        #pragma unroll
        for (int i = 0; i < IN; ++i) xr[i] = (float)xp[i];
    }
    float e_s = 0.f, e_d = sab;
    #pragma unroll
    for (int k = 0; k < HH; ++k) {
        float acc = sb[k];
        #pragma unroll
        for (int i = 0; i < IN; ++i) acc = fmaf(xr[i], sW[k * IN + i], acc);
        z[n * HH + k] = __float2half_rn(acc);
        e_s = fmaf(saW[k], acc, e_s);
        e_d = fmaf(saW[HH + k], acc, e_d);
    }
    es[n] = e_s;
    ed[n] = e_d;
}

// ---------------- per-dst attention aggregation (+elu), fp16 z, u16 csr, XCD-swizzled.
// Wave = 8 edge-rows x 8 dim-groups; lane loads 4 dims (dwordx2) of one edge per
// pass; per-lane sden accumulates weights; ONE stride-8/16/32 fold finishes both
// the weighted sums and the softmax denominator. elu via expf-1 (no expm1f libm).
template<bool WRITE_C, bool POOL>
__global__ void __launch_bounds__(256, 4)
agg_kernel(const int* __restrict__ row_ptr, const u16* __restrict__ csr,
           const __half* __restrict__ zt, const float* __restrict__ es,
           const float* __restrict__ ed, __half* __restrict__ cout,
           unsigned int* __restrict__ pooled_u, int nblk, int swz, int tadd) {
    __shared__ int2  shp[4][64];
    __shared__ float sred[4][HH];
    int t, dblk, slice;
    decode_t(nblk, swz, tadd, t, dblk, slice);
    int lane = threadIdx.x & 63;
    int w    = threadIdx.x >> 6;
    int r    = lane >> 3;     // edge-row 0..7
    int cg   = lane & 7;      // dim-group: dims cg*4 .. cg*4+3
    int d = dblk * 4 + w;
    const __half* z   = zt + (size_t)slice * NLOC * HH;
    const float*  est = es + (size_t)slice * NLOC;
    const float*  edt = ed + (size_t)slice * NLOC;

    int beg = 0, end = 0;
    float edd = 0.f;
    if (d < NLOC) {
        beg = row_ptr[d];
        end = row_ptr[d + 1];
        edd = edt[d];
    }
    int deg = end - beg;
    // preload: one coalesced u16 idx load + one es gather -> per-edge weight
    int il = beg + lane;
    bool valid = (il < end);
    int idx_l = valid ? (int)csr[il] : 0;
    float ev = est[idx_l] + edd;
    ev = (ev > 0.f) ? ev : 0.01f * ev;             // leaky_relu
    float w_l = valid ? __expf(ev) : 0.f;
    shp[w][lane] = make_int2(idx_l, __float_as_int(w_l));
    __syncthreads();

    // main loop: 8 passes x (1 LDS pair read + 1 dwordx2 z load + 4 fma + 1 add)
    float a0 = 0.f, a1 = 0.f, a2 = 0.f, a3 = 0.f, sden = 0.f;
    #pragma unroll
    for (int pass = 0; pass < 8; ++pass) {
        int2 pw = shp[w][pass * 8 + r];
        float we = __int_as_float(pw.y);
        const __half2* zp = (const __half2*)(z + (size_t)pw.x * HH + cg * 4);
        __half2 h01 = zp[0], h23 = zp[1];
        sden += we;
        a0 = fmaf(we, __half2float(__low2half(h01)),  a0);
        a1 = fmaf(we, __half2float(__high2half(h01)), a1);
        a2 = fmaf(we, __half2float(__low2half(h23)),  a2);
        a3 = fmaf(we, __half2float(__high2half(h23)), a3);
    }
    // tail for deg > 64 (not taken on this graph; correctness only)
    for (int e = 64 + r; e < deg; e += 8) {
        int s2 = (int)csr[beg + e];
        float ee = est[s2] + edd;
        ee = (ee > 0.f) ? ee : 0.01f * ee;
        float xx = __expf(ee);
        sden += xx;
        const __half2* zp = (const __half2*)(z + (size_t)s2 * HH + cg * 4);
        __half2 h01 = zp[0], h23 = zp[1];
        a0 = fmaf(xx, __half2float(__low2half(h01)),  a0);
        a1 = fmaf(xx, __half2float(__high2half(h01)), a1);
        a2 = fmaf(xx, __half2float(__low2half(h23)),  a2);
        a3 = fmaf(xx, __half2float(__high2half(h23)), a3);
    }
    // fold edge-rows (strides 8,16,32): completes weighted sums AND denominator
    #pragma unroll
    for (int o = 8; o <= 32; o <<= 1) {
        a0 += __shfl_xor(a0, o, 64);
        a1 += __shfl_xor(a1, o, 64);
        a2 += __shfl_xor(a2, o, 64);
        a3 += __shfl_xor(a3, o, 64);
        sden += __shfl_xor(sden, o, 64);
    }

    float v0 = -FLT_MAX, v1 = -FLT_MAX, v2 = -FLT_MAX, v3 = -FLT_MAX;
    if (d < NLOC) {
        float rden = 1.f / sden;
        v0 = a0 * rden; v0 = (v0 > 0.f) ? v0 : __expf(v0) - 1.f;   // elu
        v1 = a1 * rden; v1 = (v1 > 0.f) ? v1 : __expf(v1) - 1.f;
        v2 = a2 * rden; v2 = (v2 > 0.f) ? v2 : __expf(v2) - 1.f;
        v3 = a3 * rden; v3 = (v3 > 0.f) ? v3 : __expf(v3) - 1.f;
        if (WRITE_C && r == 0) {
            __half2 o01 = __floats2half2_rn(v0, v1);
            __half2 o23 = __floats2half2_rn(v2, v3);
            uint2 pk;
            pk.x = *(unsigned int*)&o01;
            pk.y = *(unsigned int*)&o23;
            *(uint2*)&cout[(size_t)slice * NLOC * HH + (size_t)d * HH + cg * 4] = pk;
        }
    }
    if (POOL) {
        if (r == 0) {
            sred[w][cg * 4 + 0] = v0;
            sred[w][cg * 4 + 1] = v1;
            sred[w][cg * 4 + 2] = v2;
            sred[w][cg * 4 + 3] = v3;
        }
        __syncthreads();
        if (threadIdx.x < HH) {
            float m = fmaxf(fmaxf(sred[0][threadIdx.x], sred[1][threadIdx.x]),
                            fmaxf(sred[2][threadIdx.x], sred[3][threadIdx.x]));
            atomicMax(&pooled_u[(size_t)(t * HH + threadIdx.x) * PSTR], fkey(m));
        }
    }
}

// ---------------- GRU over all 24 steps + heads, single block
__global__ void gru_all_kernel(const unsigned int* __restrict__ pooled_u,
                               const float* __restrict__ Wih, const float* __restrict__ Whh,
                               const float* __restrict__ bih, const float* __restrict__ bhh,
                               const float* __restrict__ WI, const float* __restrict__ bI,
                               const float* __restrict__ WR, const float* __restrict__ bR,
                               const float* __restrict__ Ws, const float* __restrict__ bs,
                               const float* __restrict__ cIv, const float* __restrict__ cRv,
                               const float* __restrict__ h0, float* __restrict__ abArr,
                               float* __restrict__ out_newI, float* __restrict__ out_newR,
                               float* __restrict__ h_fin) {
    __shared__ float pooled[HH], hs[HH], gi[96], gh[96], hc[34];
    int tid = threadIdx.x;
    float wih_r[HH], whh_r[HH];
    if (tid < 96) {
        #pragma unroll
        for (int k = 0; k < HH; ++k) {
            wih_r[k] = Wih[tid * HH + k];
            whh_r[k] = Whh[tid * HH + k];
        }
    }
    if (tid < HH) hs[tid] = h0[tid];
    __syncthreads();
    for (int t = 0; t < TT; ++t) {
        if (tid < HH) pooled[tid] = funkey(pooled_u[(size_t)(t * HH + tid) * PSTR]);
        __syncthreads();
        if (tid < 96) {
            float a = bih[tid], g = bhh[tid];
            #pragma unroll
            for (int k = 0; k < HH; ++k) {
                a = fmaf(wih_r[k], pooled[k], a);
                g = fmaf(whh_r[k], hs[k], g);
            }
            gi[tid] = a; gh[tid] = g;
        }
        __syncthreads();
        if (tid < HH) {
            float r  = 1.f / (1.f + expf(-(gi[tid] + gh[tid])));
            float zg = 1.f / (1.f + expf(-(gi[HH + tid] + gh[HH + tid])));
            float nn = tanhf(gi[2 * HH + tid] + r * gh[2 * HH + tid]);
            float hn = (1.f - zg) * nn + zg * hs[tid];
            hs[tid] = hn;
            hc[tid] = hn;
        }
        if (tid == 32) hc[32] = cIv[t];
        if (tid == 33) hc[33] = cRv[t];
        __syncthreads();
        if (tid < PWN) {
            float a = bI[tid];
            #pragma unroll
            for (int k = 0; k < 34; ++k) a = fmaf(WI[tid * 34 + k], hc[k], a);
            out_newI[t * PWN + tid] = a;
        } else if (tid >= 32 && tid < 32 + PWN) {
            int p = tid - 32;
            float a = bR[p];
            #pragma unroll
            for (int k = 0; k < 34; ++k) a = fmaf(WR[p * 34 + k], hc[k], a);
            out_newR[t * PWN + p] = a;
        } else if (tid == 64 || tid == 65) {
            int p = tid - 64;
            float a = bs[p];
            #pragma unroll
            for (int k = 0; k < 34; ++k) a = fmaf(Ws[p * 34 + k], hc[k], a);
            abArr[2 * t + p] = 1.f / (1.f + expf(-a));
        }
        __syncthreads();
    }
    if (tid < HH) h_fin[tid] = hs[tid];
}

// ---------------- SIR rollout for all (n, t)
__global__ void sir_kernel(const float* __restrict__ Nin, const float* __restrict__ Iv,
                           const float* __restrict__ Rv, const float* __restrict__ abArr,
                           float* __restrict__ phyI, float* __restrict__ phyR) {
    int idx = blockIdx.x * blockDim.x + threadIdx.x; // n*TT + t
    if (idx >= NLOC * TT) return;
    int n = idx / TT, t = idx - n * TT;
    float Nv = Nin[n];
    float alpha = abArr[2 * t], beta = abArr[2 * t + 1];
    float lI = Iv[t], lR = Rv[t];
    float* oI = phyI + (size_t)idx * PWN;
    float* oR = phyR + (size_t)idx * PWN;
    #pragma unroll
    for (int p = 0; p < PWN; ++p) {
        float lS = Nv - lI - lR;
        float dI = alpha * lI * (lS / Nv) - beta * lI;
        float dR = beta * lI;
        oI[p] = dI;
        oR[p] = dR;
        lI += dI;
        lR += dR;
    }
}

extern "C" void kernel_launch(void* const* d_in, const int* in_sizes, int n_in,
                              void* d_out, int out_size, void* d_ws, size_t ws_size,
                              hipStream_t stream) {
    const float* dynamic = (const float*)d_in[0];
    const float* cIv = (const float*)d_in[1];
    const float* cRv = (const float*)d_in[2];
    const float* Nin = (const float*)d_in[3];
    const float* Iv  = (const float*)d_in[4];
    const float* Rv  = (const float*)d_in[5];
    const float* h0  = (const float*)d_in[6];
    const float* W1  = (const float*)d_in[7];
    const float* b1  = (const float*)d_in[8];
    const float* aW1 = (const float*)d_in[9];
    const float* ab1 = (const float*)d_in[10];
    const float* W2  = (const float*)d_in[11];
    const float* b2  = (const float*)d_in[12];
    const float* aW2 = (const float*)d_in[13];
    const float* ab2 = (const float*)d_in[14];
    const float* Wih = (const float*)d_in[15];
    const float* Whh = (const float*)d_in[16];
    const float* bih = (const float*)d_in[17];
    const float* bhh = (const float*)d_in[18];
    const float* WI  = (const float*)d_in[19];
    const float* bI  = (const float*)d_in[20];
    const float* WR  = (const float*)d_in[21];
    const float* bR  = (const float*)d_in[22];
    const float* Ws  = (const float*)d_in[23];
    const float* bs  = (const float*)d_in[24];
    const int* esrc  = (const int*)d_in[25];
    const int* edst  = (const int*)d_in[26];
    const int E = in_sizes[25];

    float* out = (float*)d_out;
    float* out_newI = out;                         // (1,24,15)
    float* out_newR = out + TT * PWN;              // (1,24,15)
    float* phyI = out + 2 * TT * PWN;              // (20000,24,15)
    float* phyR = phyI + (size_t)NLOC * TT * PWN;
    float* h_fin = phyR + (size_t)NLOC * TT * PWN; // (1,32)

    // ---------------- workspace layout ----------------
    char* p = (char*)d_ws;
    int* cnt = (int*)p;                 p += (size_t)NLOC * 4;
    int* fill = (int*)p;                p += (size_t)NLOC * 4;
    int* row_ptr = (int*)p;             p += (size_t)(NLOC + 2) * 4;
    u16* csr = (u16*)p;                 p += ((size_t)E * 2 + 15) & ~(size_t)15;
    unsigned int* pooled_u = (unsigned int*)p; p += (size_t)TT * HH * PSTR * 4;
    float* abArr = (float*)p;           p += (size_t)2 * TT * 4;
    p = (char*)(((size_t)p + 15) & ~(size_t)15);
    size_t fixed_bytes = (size_t)(p - (char*)d_ws);
    size_t per_t_bytes = (size_t)(2 * NLOC * HH * 2 + 2 * NLOC * 4);
    int B = 1;
    if (ws_size > fixed_bytes + per_t_bytes)
        B = (int)((ws_size - fixed_bytes) / per_t_bytes);
    if (B > TT) B = TT;
    if (B < 1) B = 1;
    __half* zb  = (__half*)p;                       // B * NLOC*HH fp16
    __half* cb  = zb + (size_t)B * NLOC * HH;       // B * NLOC*HH fp16
    float* esb  = (float*)(cb + (size_t)B * NLOC * HH);
    float* edb  = esb + (size_t)B * NLOC;

    hipMemsetAsync(cnt, 0, (size_t)2 * NLOC * 4, stream);
    hipMemsetAsync(pooled_u, 0, (size_t)TT * HH * PSTR * 4, stream);

    int egrid = (E + 255) / 256;
    count_kernel<<<egrid, 256, 0, stream>>>(edst, cnt, E);
    scan_kernel<<<1, 1024, 0, stream>>>(cnt, row_ptr, NLOC);
    scatter_kernel<<<egrid, 256, 0, stream>>>(esrc, edst, row_ptr, fill, csr, E);

    const int NBLK_N = (NLOC + 255) / 256;   // 79
    const int NBLK_A = (NLOC + 3) / 4;       // 5000

    if (B >= TT) {
        // full batch: XCD-swizzled flat grids (all work for t on XCD t%8)
        dim3 ng(NBLK_N * TT), ag(NBLK_A * TT);
        node_kernel<INDIM, true, float><<<ng, 256, 0, stream>>>(
            dynamic, (long)TT * INDIM, (long)INDIM, W1, b1, aW1, ab1,
            zb, esb, edb, NBLK_N, 1, 0);
        agg_kernel<true, false><<<ag, 256, 0, stream>>>(
            row_ptr, csr, zb, esb, edb, cb, pooled_u, NBLK_A, 1, 0);
        node_kernel<HH, false, __half><<<ng, 256, 0, stream>>>(
            cb, (long)HH, (long)NLOC * HH, W2, b2, aW2, ab2,
            zb, esb, edb, NBLK_N, 1, 0);
        agg_kernel<false, true><<<ag, 256, 0, stream>>>(
            row_ptr, csr, zb, esb, edb, nullptr, pooled_u, NBLK_A, 1, 0);
    } else {
        for (int tbase = 0; tbase < TT; tbase += B) {
            int Bc = TT - tbase; if (Bc > B) Bc = B;
            dim3 ng(NBLK_N, Bc), ag(NBLK_A, Bc);
            node_kernel<INDIM, true, float><<<ng, 256, 0, stream>>>(
                dynamic, (long)TT * INDIM, (long)INDIM, W1, b1, aW1, ab1,
                zb, esb, edb, NBLK_N, 0, tbase);
            agg_kernel<true, false><<<ag, 256, 0, stream>>>(
                row_ptr, csr, zb, esb, edb, cb, pooled_u, NBLK_A, 0, tbase);
            node_kernel<HH, false, __half><<<ng, 256, 0, stream>>>(
                cb, (long)HH, (long)NLOC * HH, W2, b2, aW2, ab2,
                zb, esb, edb, NBLK_N, 0, tbase);
            agg_kernel<false, true><<<ag, 256, 0, stream>>>(
                row_ptr, csr, zb, esb, edb, nullptr, pooled_u, NBLK_A, 0, tbase);
        }
    }

    gru_all_kernel<<<1, 128, 0, stream>>>(pooled_u, Wih, Whh, bih, bhh,
                                          WI, bI, WR, bR, Ws, bs, cIv, cRv,
                                          h0, abArr, out_newI, out_newR, h_fin);
    sir_kernel<<<(NLOC * TT + 255) / 256, 256, 0, stream>>>(Nin, Iv, Rv, abArr, phyI, phyR);
}